// Round 20
// baseline (165.815 us; speedup 1.0000x reference)
//
#include <hip/hip_runtime.h>
#include <stdint.h>

#define EMBED 1024
#define HEAD  256
#define BATCH 8
#define SEQ   2048
#define NTOK  (BATCH*SEQ)

typedef __attribute__((ext_vector_type(8)))  short  s16x8;
typedef __attribute__((ext_vector_type(4)))  float  f32x4;
typedef __attribute__((ext_vector_type(16))) float  f32x16;
typedef __attribute__((ext_vector_type(4)))  unsigned short u16x4;

__device__ __forceinline__ unsigned short f2bf(float f) {
  union { float f; uint32_t u; } v; v.f = f;
  return (unsigned short)((v.u + 0x7FFFu + ((v.u >> 16) & 1u)) >> 16);
}

__device__ __forceinline__ float b2f(unsigned short u) {
  union { uint32_t u; float f; } v; v.u = (uint32_t)u << 16; return v.f;
}

__device__ __forceinline__ uint32_t cvtpk(float a, float b) {
  uint32_t r;
  asm("v_cvt_pk_bf16_f32 %0, %1, %2" : "=v"(r) : "v"(a), "v"(b));
  return r;
}

__device__ __forceinline__ void gload_lds16(const void* g, void* l) {
  __builtin_amdgcn_global_load_lds((const __attribute__((address_space(1))) void*)g,
                                   (__attribute__((address_space(3))) void*)l, 16, 0, 0);
}

// ---------------- K0a: weights -> Wt bf16; fold (1/16)*log2(e) into Wq -------------
// (scores produced in log2 domain -> exp2 replaces exp everywhere downstream)
__global__ __launch_bounds__(256) void wt_kernel(const float* __restrict__ Wq,
                                                 const float* __restrict__ Wk,
                                                 const float* __restrict__ Wv,
                                                 unsigned short* __restrict__ Wt) {
  int idx = blockIdx.x * 256 + threadIdx.x;
  int e  = idx & (EMBED - 1);
  int hw = idx >> 10;
  int w  = hw >> 8;
  int h  = hw & 255;
  const float* W = (w == 0) ? Wq : (w == 1) ? Wk : Wv;
  float sc = (w == 0) ? 0.09016844f : 1.0f;   // 0.0625 * log2(e)
  Wt[idx] = f2bf(W[(size_t)e * HEAD + h] * sc);
}

// ---------------- K0b: x fp32 -> xb bf16 (once) ----------------
__global__ __launch_bounds__(256) void xprep_kernel(const float* __restrict__ x,
                                                    unsigned short* __restrict__ xb) {
  size_t i8 = ((size_t)blockIdx.x * 256 + threadIdx.x) * 8;
  f32x4 f0 = *(const f32x4*)(x + i8);
  f32x4 f1 = *(const f32x4*)(x + i8 + 4);
  u16x4 p0, p1;
  #pragma unroll
  for (int j = 0; j < 4; j++) { p0[j] = f2bf(f0[j]); p1[j] = f2bf(f1[j]); }
  *(u16x4*)(xb + i8)     = p0;
  *(u16x4*)(xb + i8 + 4) = p1;
}

// ---------------- K1: QKV projection GEMM (global_load_lds, XCD-chunked) -----------
__global__ __launch_bounds__(256) void proj_kernel(const unsigned short* __restrict__ xb,
    const unsigned short* __restrict__ Wt,
    unsigned short* __restrict__ qo, unsigned short* __restrict__ ko,
    unsigned short* __restrict__ vfrag) {
  __shared__ unsigned short Al[128 * 64];
  __shared__ unsigned short Bl[128 * 64];
  const int tid  = threadIdx.x;
  const int lane = tid & 63;
  const int wid  = tid >> 6;
  const int wm = wid >> 1, wn = wid & 1;
  const int bid  = blockIdx.x;
  const int xcd  = bid & 7;
  const int i6   = bid >> 3;          // 0..95
  const int mloc = i6 & 15;
  const int nz   = i6 >> 4;           // 0..5
  const int m0 = (xcd * 16 + mloc) * 128;
  const int n0 = (nz & 1) * 128;
  const int w  = nz >> 1;
  const unsigned short* Wtw = Wt + (size_t)w * 256 * EMBED;

  f32x4 acc[4][4] = {};

  for (int k0 = 0; k0 < EMBED; k0 += 64) {
    #pragma unroll
    for (int i = 0; i < 4; i++) {
      int u = tid + 256 * i;
      int row = u >> 3, sc = u & 7;
      gload_lds16(xb + (size_t)(m0 + row) * EMBED + k0 + sc * 8,
                  &Al[i * 2048 + wid * 512]);
    }
    #pragma unroll
    for (int i = 0; i < 4; i++) {
      int u = tid + 256 * i;
      int row = u >> 3, sc = u & 7;
      gload_lds16(Wtw + (size_t)(n0 + row) * EMBED + k0 + sc * 8,
                  &Bl[i * 2048 + wid * 512]);
    }
    __syncthreads();
    #pragma unroll
    for (int kk = 0; kk < 2; kk++) {
      s16x8 a[4], bfr[4];
      #pragma unroll
      for (int mi = 0; mi < 4; mi++) {
        int row = wm * 64 + mi * 16 + (lane & 15);
        a[mi] = *(const s16x8*)(&Al[row * 64 + kk * 32 + 8 * (lane >> 4)]);
      }
      #pragma unroll
      for (int ni = 0; ni < 4; ni++) {
        int row = wn * 64 + ni * 16 + (lane & 15);
        bfr[ni] = *(const s16x8*)(&Bl[row * 64 + kk * 32 + 8 * (lane >> 4)]);
      }
      #pragma unroll
      for (int mi = 0; mi < 4; mi++)
        #pragma unroll
        for (int ni = 0; ni < 4; ni++)
          acc[mi][ni] = __builtin_amdgcn_mfma_f32_16x16x32_bf16(a[mi], bfr[ni], acc[mi][ni], 0, 0, 0);
    }
    __syncthreads();
  }

  if (w < 2) {
    unsigned short* dst = (w == 0) ? qo : ko;
    #pragma unroll
    for (int mi = 0; mi < 4; mi++)
      #pragma unroll
      for (int r = 0; r < 4; r++) {
        int mrow = m0 + wm * 64 + mi * 16 + 4 * (lane >> 4) + r;
        #pragma unroll
        for (int ni = 0; ni < 4; ni++) {
          int col = n0 + wn * 64 + ni * 16 + (lane & 15);
          dst[(size_t)mrow * HEAD + col] = f2bf(acc[mi][ni][r]);
        }
      }
  } else {
    // V: fragment-order write (verified r15)
    #pragma unroll
    for (int mi = 0; mi < 4; mi++) {
      int base = m0 + wm * 64 + mi * 16 + 4 * (lane >> 4);
      int toko = base & 31;
      size_t vb0 = (size_t)(base >> 11) * 524288
                 + (size_t)((base & 2047) >> 5) * 8192
                 + ((toko >> 4) & 1) * 512 + ((toko >> 3) & 1) * 256 + (toko & 7);
      #pragma unroll
      for (int ni = 0; ni < 4; ni++) {
        int col = n0 + wn * 64 + ni * 16 + (lane & 15);
        u16x4 pk;
        #pragma unroll
        for (int r = 0; r < 4; r++) pk[r] = f2bf(acc[mi][ni][r]);
        *(u16x4*)(vfrag + vb0 + (size_t)(col >> 5) * 1024 + (col & 31) * 8) = pk;
      }
    }
  }
}

// ---------------- K2: causal flash attention, key-half split blocks -----------------
// 512 blocks x 4 waves, ALL co-resident (2 blocks/CU). Block (batch, pair p, half h)
// handles slab 63-p then slab p, restricted to key-half h of each slab -> max 9
// tiles/wave (wall ~ tiles/wave x serial chain, measured r12/r15/r19). Each slab's
// 4-wave in-block merge emits a PARTIAL (o-sum bf16, m, L) to ws; fmerge combines
// the two halves. Scores in log2 domain (exp2).
__global__ __launch_bounds__(256, 1) void attn_kernel(const unsigned short* __restrict__ qb,
    const unsigned short* __restrict__ kb, const unsigned short* __restrict__ vfrag,
    unsigned short* __restrict__ po, float* __restrict__ pml) {
  __shared__ unsigned short Kl[4][32 * 256];   // 4 x 16 KB wave-private
  __shared__ float mls[4][2][32];
  const int tid  = threadIdx.x;
  const int lane = tid & 63;
  const int w    = tid >> 6;                 // wave = key chunk 0..3
  const int hi   = lane >> 5;
  const int q    = lane & 31;
  const int bid  = blockIdx.x;
  const int b  = bid & 7;                    // batch -> XCD affinity
  const int r2 = bid >> 3;                   // 0..63
  const int p  = r2 >> 1;                    // pair 0..31
  const int h  = r2 & 1;                     // key half
  const unsigned short* qB = qb + (size_t)b * SEQ * HEAD;
  const unsigned short* kB = kb + (size_t)b * SEQ * HEAD;
  const unsigned short* vfB = vfrag + (size_t)b * 524288;
  unsigned short* Kw = (unsigned short*)Kl[w];

  for (int sl = 0; sl < 2; sl++) {
    const int t  = sl ? p : (63 - p);        // big slab first
    const int qg = t * 32 + q;

    s16x8 qf[16];
    #pragma unroll
    for (int s = 0; s < 16; s++)
      qf[s] = *(const s16x8*)(qB + (size_t)qg * HEAD + s * 16 + hi * 8);

    f32x16 o[8] = {};
    float m = -1e30f, lsum = 0.f;

    const int nt  = t + 1;                   // 32-key tiles in causal range
    const int hc0 = (nt + 1) >> 1;           // tiles in half 0
    const int st  = h ? hc0 : 0;
    const int cnt = h ? (nt - hc0) : hc0;
    const int cl  = (cnt + 3) >> 2;          // tiles per wave (<= 9 total over 2 slabs)
    const int j0  = st + w * cl;
    const int j1e = st + cnt;
    const int j1  = (j0 + cl < j1e) ? (j0 + cl) : j1e;

    for (int j = j0; j < j1; j++) {
      // ---- stage K tile j (32 keys x 256) into private LDS, src-swizzled ----
      #pragma unroll
      for (int i = 0; i < 16; i++) {
        int cl_ = i * 64 + lane;
        int key = cl_ >> 5, c = cl_ & 31;
        gload_lds16(kB + (size_t)(j * 32 + key) * HEAD + (size_t)((c ^ (key & 15)) * 8),
                    &Kw[i * 512]);
      }
      asm volatile("s_waitcnt vmcnt(0)" ::: "memory");
      __builtin_amdgcn_sched_barrier(0);
      // ---- S^T = K Q^T (2 chains) ----
      f32x16 s0 = {}, s1 = {};
      #pragma unroll
      for (int s = 0; s < 8; s++) {
        s16x8 kf = *(const s16x8*)((const char*)Kw +
                     (q * 512 + (((2 * s + hi) ^ (q & 15)) << 4)));
        s0 = __builtin_amdgcn_mfma_f32_32x32x16_bf16(kf, qf[s], s0, 0, 0, 0);
      }
      #pragma unroll
      for (int s = 8; s < 16; s++) {
        s16x8 kf = *(const s16x8*)((const char*)Kw +
                     (q * 512 + (((2 * s + hi) ^ (q & 15)) << 4)));
        s1 = __builtin_amdgcn_mfma_f32_32x32x16_bf16(kf, qf[s], s1, 0, 0, 0);
      }
      f32x16 sv;
      #pragma unroll
      for (int r = 0; r < 16; r++) sv[r] = s0[r] + s1[r];
      // ---- causal mask (diagonal tile only: j == t) ----
      if (j == t) {
        #pragma unroll
        for (int r = 0; r < 16; r++) {
          int kg = j * 32 + (r & 3) + 8 * (r >> 2) + 4 * hi;
          sv[r] = (kg > qg) ? -1e30f : sv[r];
        }
      }
      // ---- row max + defer-max rescale (THR = 8*log2e in log2 domain) ----
      float mt = sv[0];
      #pragma unroll
      for (int r = 1; r < 16; r++) mt = fmaxf(mt, sv[r]);
      mt = fmaxf(mt, __shfl_xor(mt, 32));
      float mn = fmaxf(m, mt);
      if (!__all(mt - m <= 11.5416f)) {
        float al = exp2f(m - mn);
        lsum *= al;
        #pragma unroll
        for (int ht = 0; ht < 8; ht++)
          #pragma unroll
          for (int r = 0; r < 16; r++) o[ht][r] *= al;
        m = mn;
      }
      // ---- P = exp2(S - m), row sum ----
      #pragma unroll
      for (int r = 0; r < 16; r++) sv[r] = exp2f(sv[r] - m);
      float rs = 0.f;
      #pragma unroll
      for (int r = 0; r < 16; r++) rs += sv[r];
      rs += __shfl_xor(rs, 32);
      lsum += rs;
      // ---- P^T B-frags via cvt_pk + cross-half shuffle ----
      uint32_t cc[8], dd[8];
      #pragma unroll
      for (int i = 0; i < 8; i++) cc[i] = cvtpk(sv[2 * i], sv[2 * i + 1]);
      #pragma unroll
      for (int i = 0; i < 8; i++) dd[i] = (uint32_t)__shfl_xor((int)cc[i], 32);
      union { s16x8 v; uint32_t u[4]; } pf0, pf1;
      pf0.u[0] = hi ? dd[2] : cc[0];
      pf0.u[1] = hi ? dd[3] : cc[1];
      pf0.u[2] = hi ? cc[2] : dd[0];
      pf0.u[3] = hi ? cc[3] : dd[1];
      pf1.u[0] = hi ? dd[6] : cc[4];
      pf1.u[1] = hi ? dd[7] : cc[5];
      pf1.u[2] = hi ? cc[6] : dd[4];
      pf1.u[3] = hi ? cc[7] : dd[5];
      // ---- O^T += V^T P^T (V frags in FRAGMENT ORDER) ----
      const unsigned short* vT = vfB + (size_t)j * 8192 + hi * 256 + q * 8;
      #pragma unroll
      for (int ht = 0; ht < 8; ht++) {
        s16x8 vf0 = *(const s16x8*)(vT + ht * 1024);
        o[ht] = __builtin_amdgcn_mfma_f32_32x32x16_bf16(vf0, pf0.v, o[ht], 0, 0, 0);
        s16x8 vf1 = *(const s16x8*)(vT + ht * 1024 + 512);
        o[ht] = __builtin_amdgcn_mfma_f32_32x32x16_bf16(vf1, pf1.v, o[ht], 0, 0, 0);
      }
    }

    // ---- in-block merge of 4 wave partials -> block partial (this slab/half) ----
    __syncthreads();                         // all loops done; Kl dead
    if (lane < 32) { mls[w][0][q] = m; mls[w][1][q] = lsum; }
    __syncthreads();
    float mx = mls[0][0][q];
    #pragma unroll
    for (int w2 = 1; w2 < 4; w2++) mx = fmaxf(mx, mls[w2][0][q]);
    float L = 0.f;
    #pragma unroll
    for (int w2 = 0; w2 < 4; w2++)
      L += exp2f(mls[w2][0][q] - mx) * mls[w2][1][q];
    float aown = exp2f(m - mx);
    #pragma unroll
    for (int ht = 0; ht < 8; ht++)
      #pragma unroll
      for (int r = 0; r < 16; r++) o[ht][r] *= aown;

    const int pid = (b * 64 + t) * 2 + h;
    unsigned short* poS = po + (size_t)pid * 8192;
    if (w == 0 && lane < 32) {
      pml[pid * 64 + lane] = mx;
      pml[pid * 64 + 32 + lane] = L;
    }

    // accumulate through LDS: [32 q][256 h] f32, 16B groups XOR-swizzled by q.
    float* obuf = (float*)&Kl[0][0];
    for (int ph = 3; ph >= 0; ph--) {
      if (w == ph) {
        #pragma unroll
        for (int ht = 0; ht < 8; ht++)
          #pragma unroll
          for (int g2 = 0; g2 < 4; g2++) {
            int gp = 8 * ht + 2 * g2 + hi;                 // 16B group index 0..63
            float* ptr = &obuf[q * 256 + ((gp ^ (q & 15)) << 2)];
            f32x4 v4 = { o[ht][4*g2], o[ht][4*g2+1], o[ht][4*g2+2], o[ht][4*g2+3] };
            if (ph != 3) { f32x4 prev = *(f32x4*)ptr;
              #pragma unroll
              for (int z = 0; z < 4; z++) v4[z] += prev[z]; }
            if (ph != 0) { *(f32x4*)ptr = v4; }
            else {
              u16x4 pk;
              #pragma unroll
              for (int z = 0; z < 4; z++) pk[z] = f2bf(v4[z]);
              *(u16x4*)(poS + q * 256 + ht * 32 + g2 * 8 + hi * 4) = pk;
            }
          }
      }
      __syncthreads();
    }
  }
}

// ---------------- K3: merge the two key-half partials per slab ----------------------
__global__ __launch_bounds__(256) void fmerge_kernel(const unsigned short* __restrict__ po,
    const float* __restrict__ pml, float* __restrict__ out) {
  const int blk = blockIdx.x;               // 0..511: (b, t)
  const int b = blk >> 6, t = blk & 63;
  const int tid = threadIdx.x;
  const int q = tid >> 3;                   // row within slab
  const int c0 = (tid & 7) * 32;            // col start
  const int pid0 = (b * 64 + t) * 2;
  float m0 = pml[pid0 * 64 + q],       L0 = pml[pid0 * 64 + 32 + q];
  float m1 = pml[(pid0 + 1) * 64 + q], L1 = pml[(pid0 + 1) * 64 + 32 + q];
  float M = fmaxf(m0, m1);
  float a0 = exp2f(m0 - M), a1 = exp2f(m1 - M);
  float L = a0 * L0 + a1 * L1;
  const unsigned short* p0 = po + (size_t)pid0 * 8192 + q * 256 + c0;
  const unsigned short* p1 = p0 + 8192;
  float* op = out + ((size_t)b * SEQ + t * 32 + q) * HEAD + c0;
  #pragma unroll
  for (int i = 0; i < 4; i++) {
    s16x8 x0 = *(const s16x8*)(p0 + i * 8);
    s16x8 x1 = *(const s16x8*)(p1 + i * 8);
    f32x4 lo, hi2;
    #pragma unroll
    for (int z = 0; z < 4; z++) {
      lo[z]  = (a0 * b2f((unsigned short)x0[z])     + a1 * b2f((unsigned short)x1[z]))     / L;
      hi2[z] = (a0 * b2f((unsigned short)x0[z + 4]) + a1 * b2f((unsigned short)x1[z + 4])) / L;
    }
    *(f32x4*)(op + i * 8)     = lo;
    *(f32x4*)(op + i * 8 + 4) = hi2;
  }
}

extern "C" void kernel_launch(void* const* d_in, const int* in_sizes, int n_in,
                              void* d_out, int out_size, void* d_ws, size_t ws_size,
                              hipStream_t stream) {
  const float* x  = (const float*)d_in[0];
  const float* Wq = (const float*)d_in[1];
  const float* Wk = (const float*)d_in[2];
  const float* Wv = (const float*)d_in[3];
  float* out = (float*)d_out;

  unsigned short* ws = (unsigned short*)d_ws;
  unsigned short* qb    = ws;                              // [16384][256] (Q pre-scaled)
  unsigned short* kb    = qb + (size_t)NTOK * HEAD;        // [16384][256] row-major
  unsigned short* vfrag = kb + (size_t)NTOK * HEAD;        // fragment-order V
  unsigned short* Wt    = vfrag + (size_t)NTOK * HEAD;     // [3][256][1024]
  unsigned short* xb    = Wt + (size_t)3 * HEAD * EMBED;   // [16384][1024] (32 MB)
  // partial buffers overlay xb (dead after proj): po 16 MB + pml 256 KB
  unsigned short* po    = xb;                              // [1024][32][256] bf16
  float*          pml   = (float*)(xb + (size_t)1024 * 8192); // [1024][2][32] f32

  hipLaunchKernelGGL(wt_kernel, dim3(3 * 256 * EMBED / 256), dim3(256), 0, stream,
                     Wq, Wk, Wv, Wt);
  hipLaunchKernelGGL(xprep_kernel, dim3(NTOK * EMBED / (256 * 8)), dim3(256), 0, stream,
                     x, xb);
  hipLaunchKernelGGL(proj_kernel, dim3(768), dim3(256), 0, stream,
                     xb, Wt, qb, kb, vfrag);
  hipLaunchKernelGGL(attn_kernel, dim3(512), dim3(256), 0, stream,
                     qb, kb, vfrag, po, pml);
  hipLaunchKernelGGL(fmerge_kernel, dim3(512), dim3(256), 0, stream,
                     po, pml, out);
}

// Round 21
// 133.481 us; speedup vs baseline: 1.2422x; 1.2422x over previous
//
#include <hip/hip_runtime.h>
#include <stdint.h>

#define EMBED 1024
#define HEAD  256
#define BATCH 8
#define SEQ   2048
#define NTOK  (BATCH*SEQ)

typedef __attribute__((ext_vector_type(8)))  short  s16x8;
typedef __attribute__((ext_vector_type(4)))  float  f32x4;
typedef __attribute__((ext_vector_type(16))) float  f32x16;
typedef __attribute__((ext_vector_type(4)))  unsigned short u16x4;

__device__ __forceinline__ unsigned short f2bf(float f) {
  union { float f; uint32_t u; } v; v.f = f;
  return (unsigned short)((v.u + 0x7FFFu + ((v.u >> 16) & 1u)) >> 16);
}

__device__ __forceinline__ uint32_t cvtpk(float a, float b) {
  uint32_t r;
  asm("v_cvt_pk_bf16_f32 %0, %1, %2" : "=v"(r) : "v"(a), "v"(b));
  return r;
}

__device__ __forceinline__ void gload_lds16(const void* g, void* l) {
  __builtin_amdgcn_global_load_lds((const __attribute__((address_space(1))) void*)g,
                                   (__attribute__((address_space(3))) void*)l, 16, 0, 0);
}

// ---------------- K0a: weights -> Wt bf16 [3][256 h][1024 e]; fold 1/16 into Wq ----
__global__ __launch_bounds__(256) void wt_kernel(const float* __restrict__ Wq,
                                                 const float* __restrict__ Wk,
                                                 const float* __restrict__ Wv,
                                                 unsigned short* __restrict__ Wt) {
  int idx = blockIdx.x * 256 + threadIdx.x;
  int e  = idx & (EMBED - 1);
  int hw = idx >> 10;
  int w  = hw >> 8;
  int h  = hw & 255;
  const float* W = (w == 0) ? Wq : (w == 1) ? Wk : Wv;
  float sc = (w == 0) ? 0.0625f : 1.0f;
  Wt[idx] = f2bf(W[(size_t)e * HEAD + h] * sc);
}

// ---------------- K0b: x fp32 -> xb bf16 (once) ----------------
__global__ __launch_bounds__(256) void xprep_kernel(const float* __restrict__ x,
                                                    unsigned short* __restrict__ xb) {
  size_t i8 = ((size_t)blockIdx.x * 256 + threadIdx.x) * 8;
  f32x4 f0 = *(const f32x4*)(x + i8);
  f32x4 f1 = *(const f32x4*)(x + i8 + 4);
  u16x4 p0, p1;
  #pragma unroll
  for (int j = 0; j < 4; j++) { p0[j] = f2bf(f0[j]); p1[j] = f2bf(f1[j]); }
  *(u16x4*)(xb + i8)     = p0;
  *(u16x4*)(xb + i8 + 4) = p1;
}

// ---------------- K1: QKV projection GEMM (global_load_lds, XOR-swizzled LDS) ------
// LDS tiles are [128 rows][8 chunks of 16B]; chunk c of row r is stored at LDS slot
// c^(r&7) via PRE-SWIZZLED global source (linear LDS dest, rule: both-sides-or-
// neither). Fragment reads apply the same XOR -> bank conflicts 16-way -> 2-way
// (free). This was proj's bottleneck (~256 conflicted ds_read_b128/wave).
__global__ __launch_bounds__(256) void proj_kernel(const unsigned short* __restrict__ xb,
    const unsigned short* __restrict__ Wt,
    unsigned short* __restrict__ qo, unsigned short* __restrict__ ko,
    unsigned short* __restrict__ vfrag) {
  __shared__ unsigned short Al[128 * 64];
  __shared__ unsigned short Bl[128 * 64];
  const int tid  = threadIdx.x;
  const int lane = tid & 63;
  const int wid  = tid >> 6;
  const int wm = wid >> 1, wn = wid & 1;
  const int bid  = blockIdx.x;
  const int xcd  = bid & 7;
  const int i6   = bid >> 3;          // 0..95
  const int mloc = i6 & 15;
  const int nz   = i6 >> 4;           // 0..5
  const int m0 = (xcd * 16 + mloc) * 128;
  const int n0 = (nz & 1) * 128;
  const int w  = nz >> 1;
  const unsigned short* Wtw = Wt + (size_t)w * 256 * EMBED;

  f32x4 acc[4][4] = {};

  for (int k0 = 0; k0 < EMBED; k0 += 64) {
    #pragma unroll
    for (int i = 0; i < 4; i++) {
      int u = tid + 256 * i;
      int row = u >> 3, sc = u & 7;
      int scs = sc ^ (row & 7);       // pre-swizzled source chunk
      gload_lds16(xb + (size_t)(m0 + row) * EMBED + k0 + scs * 8,
                  &Al[i * 2048 + wid * 512]);
    }
    #pragma unroll
    for (int i = 0; i < 4; i++) {
      int u = tid + 256 * i;
      int row = u >> 3, sc = u & 7;
      int scs = sc ^ (row & 7);
      gload_lds16(Wtw + (size_t)(n0 + row) * EMBED + k0 + scs * 8,
                  &Bl[i * 2048 + wid * 512]);
    }
    __syncthreads();
    #pragma unroll
    for (int kk = 0; kk < 2; kk++) {
      s16x8 a[4], bfr[4];
      #pragma unroll
      for (int mi = 0; mi < 4; mi++) {
        int row = wm * 64 + mi * 16 + (lane & 15);
        int c = (4 * kk + (lane >> 4)) ^ (row & 7);
        a[mi] = *(const s16x8*)(&Al[row * 64 + c * 8]);
      }
      #pragma unroll
      for (int ni = 0; ni < 4; ni++) {
        int row = wn * 64 + ni * 16 + (lane & 15);
        int c = (4 * kk + (lane >> 4)) ^ (row & 7);
        bfr[ni] = *(const s16x8*)(&Bl[row * 64 + c * 8]);
      }
      #pragma unroll
      for (int mi = 0; mi < 4; mi++)
        #pragma unroll
        for (int ni = 0; ni < 4; ni++)
          acc[mi][ni] = __builtin_amdgcn_mfma_f32_16x16x32_bf16(a[mi], bfr[ni], acc[mi][ni], 0, 0, 0);
    }
    __syncthreads();
  }

  if (w < 2) {
    unsigned short* dst = (w == 0) ? qo : ko;
    #pragma unroll
    for (int mi = 0; mi < 4; mi++)
      #pragma unroll
      for (int r = 0; r < 4; r++) {
        int mrow = m0 + wm * 64 + mi * 16 + 4 * (lane >> 4) + r;
        #pragma unroll
        for (int ni = 0; ni < 4; ni++) {
          int col = n0 + wn * 64 + ni * 16 + (lane & 15);
          dst[(size_t)mrow * HEAD + col] = f2bf(acc[mi][ni][r]);
        }
      }
  } else {
    // V: fragment-order write (verified r15)
    #pragma unroll
    for (int mi = 0; mi < 4; mi++) {
      int base = m0 + wm * 64 + mi * 16 + 4 * (lane >> 4);
      int toko = base & 31;
      size_t vb0 = (size_t)(base >> 11) * 524288
                 + (size_t)((base & 2047) >> 5) * 8192
                 + ((toko >> 4) & 1) * 512 + ((toko >> 3) & 1) * 256 + (toko & 7);
      #pragma unroll
      for (int ni = 0; ni < 4; ni++) {
        int col = n0 + wn * 64 + ni * 16 + (lane & 15);
        u16x4 pk;
        #pragma unroll
        for (int r = 0; r < 4; r++) pk[r] = f2bf(acc[mi][ni][r]);
        *(u16x4*)(vfrag + vb0 + (size_t)(col >> 5) * 1024 + (col & 31) * 8) = pk;
      }
    }
  }
}

// ---------------- K2: causal flash attention (r15 verified, best: 72.4 us) ----------
__global__ __launch_bounds__(256, 1) void attn_kernel(const unsigned short* __restrict__ qb,
    const unsigned short* __restrict__ kb, const unsigned short* __restrict__ vfrag,
    float* __restrict__ out) {
  __shared__ unsigned short Kl[4][32 * 256];   // 4 x 16 KB wave-private
  __shared__ float mls[4][2][32];
  const int tid  = threadIdx.x;
  const int lane = tid & 63;
  const int w    = tid >> 6;                 // wave = key chunk 0..3
  const int hi   = lane >> 5;
  const int q    = lane & 31;
  const int bid  = blockIdx.x;
  const int b = bid & 7;                     // batch -> XCD affinity
  const int t = 63 - (bid >> 3);             // LPT: big slabs first
  const unsigned short* qB = qb + (size_t)b * SEQ * HEAD;
  const unsigned short* kB = kb + (size_t)b * SEQ * HEAD;
  const unsigned short* vfB = vfrag + (size_t)b * 524288;
  float* outB = out + (size_t)b * SEQ * HEAD;
  const int qg = t * 32 + q;                 // this lane's q-row

  s16x8 qf[16];
  #pragma unroll
  for (int s = 0; s < 16; s++)
    qf[s] = *(const s16x8*)(qB + (size_t)qg * HEAD + s * 16 + hi * 8);

  f32x16 o[8] = {};
  float m = -1e30f, lsum = 0.f;

  const int nt = t + 1;                      // 32-key tiles in causal range
  const int cl = (nt + 3) >> 2;
  const int j0 = w * cl;
  const int j1 = (j0 + cl < nt) ? (j0 + cl) : nt;
  unsigned short* Kw = (unsigned short*)Kl[w];

  for (int j = j0; j < j1; j++) {
    // ---- stage K tile j (32 keys x 256) into private LDS, src-swizzled ----
    #pragma unroll
    for (int i = 0; i < 16; i++) {
      int cl_ = i * 64 + lane;
      int key = cl_ >> 5, c = cl_ & 31;
      gload_lds16(kB + (size_t)(j * 32 + key) * HEAD + (size_t)((c ^ (key & 15)) * 8),
                  &Kw[i * 512]);
    }
    asm volatile("s_waitcnt vmcnt(0)" ::: "memory");
    __builtin_amdgcn_sched_barrier(0);
    // ---- S^T = K Q^T (2 chains) ----
    f32x16 s0 = {}, s1 = {};
    #pragma unroll
    for (int s = 0; s < 8; s++) {
      s16x8 kf = *(const s16x8*)((const char*)Kw +
                   (q * 512 + (((2 * s + hi) ^ (q & 15)) << 4)));
      s0 = __builtin_amdgcn_mfma_f32_32x32x16_bf16(kf, qf[s], s0, 0, 0, 0);
    }
    #pragma unroll
    for (int s = 8; s < 16; s++) {
      s16x8 kf = *(const s16x8*)((const char*)Kw +
                   (q * 512 + (((2 * s + hi) ^ (q & 15)) << 4)));
      s1 = __builtin_amdgcn_mfma_f32_32x32x16_bf16(kf, qf[s], s1, 0, 0, 0);
    }
    f32x16 sv;
    #pragma unroll
    for (int r = 0; r < 16; r++) sv[r] = s0[r] + s1[r];
    // ---- causal mask (diagonal tile only: j == t) ----
    if (j == t) {
      #pragma unroll
      for (int r = 0; r < 16; r++) {
        int kg = j * 32 + (r & 3) + 8 * (r >> 2) + 4 * hi;
        sv[r] = (kg > qg) ? -1e30f : sv[r];
      }
    }
    // ---- row max + defer-max rescale (THR=8) ----
    float mt = sv[0];
    #pragma unroll
    for (int r = 1; r < 16; r++) mt = fmaxf(mt, sv[r]);
    mt = fmaxf(mt, __shfl_xor(mt, 32));
    float mn = fmaxf(m, mt);
    if (!__all(mt - m <= 8.0f)) {
      float al = __expf(m - mn);
      lsum *= al;
      #pragma unroll
      for (int ht = 0; ht < 8; ht++)
        #pragma unroll
        for (int r = 0; r < 16; r++) o[ht][r] *= al;
      m = mn;
    }
    // ---- P = exp(S - m), row sum ----
    #pragma unroll
    for (int r = 0; r < 16; r++) sv[r] = __expf(sv[r] - m);
    float rs = 0.f;
    #pragma unroll
    for (int r = 0; r < 16; r++) rs += sv[r];
    rs += __shfl_xor(rs, 32);
    lsum += rs;
    // ---- P^T B-frags via cvt_pk + cross-half shuffle ----
    uint32_t cc[8], dd[8];
    #pragma unroll
    for (int i = 0; i < 8; i++) cc[i] = cvtpk(sv[2 * i], sv[2 * i + 1]);
    #pragma unroll
    for (int i = 0; i < 8; i++) dd[i] = (uint32_t)__shfl_xor((int)cc[i], 32);
    union { s16x8 v; uint32_t u[4]; } pf0, pf1;
    pf0.u[0] = hi ? dd[2] : cc[0];
    pf0.u[1] = hi ? dd[3] : cc[1];
    pf0.u[2] = hi ? cc[2] : dd[0];
    pf0.u[3] = hi ? cc[3] : dd[1];
    pf1.u[0] = hi ? dd[6] : cc[4];
    pf1.u[1] = hi ? dd[7] : cc[5];
    pf1.u[2] = hi ? cc[6] : dd[4];
    pf1.u[3] = hi ? cc[7] : dd[5];
    // ---- O^T += V^T P^T (V frags in FRAGMENT ORDER, contiguous 1KB/instr) ----
    const unsigned short* vT = vfB + (size_t)j * 8192 + hi * 256 + q * 8;
    #pragma unroll
    for (int ht = 0; ht < 8; ht++) {
      s16x8 vf0 = *(const s16x8*)(vT + ht * 1024);
      o[ht] = __builtin_amdgcn_mfma_f32_32x32x16_bf16(vf0, pf0.v, o[ht], 0, 0, 0);
      s16x8 vf1 = *(const s16x8*)(vT + ht * 1024 + 512);
      o[ht] = __builtin_amdgcn_mfma_f32_32x32x16_bf16(vf1, pf1.v, o[ht], 0, 0, 0);
    }
  }

  // ---- flash-decoding merge of 4 wave partials ----
  __syncthreads();                           // all loops done; Kl dead
  if (lane < 32) { mls[w][0][q] = m; mls[w][1][q] = lsum; }
  __syncthreads();
  float mx = mls[0][0][q];
  #pragma unroll
  for (int w2 = 1; w2 < 4; w2++) mx = fmaxf(mx, mls[w2][0][q]);
  float L = 0.f;
  #pragma unroll
  for (int w2 = 0; w2 < 4; w2++)
    L += __expf(mls[w2][0][q] - mx) * mls[w2][1][q];
  float aown = __expf(m - mx);
  #pragma unroll
  for (int ht = 0; ht < 8; ht++)
    #pragma unroll
    for (int r = 0; r < 16; r++) o[ht][r] *= aown;

  // accumulate through LDS: [32 q][256 h] f32, 16B groups XOR-swizzled by q.
  float* obuf = (float*)&Kl[0][0];
  for (int ph = 3; ph >= 0; ph--) {
    if (w == ph) {
      #pragma unroll
      for (int ht = 0; ht < 8; ht++)
        #pragma unroll
        for (int g2 = 0; g2 < 4; g2++) {
          int gp = 8 * ht + 2 * g2 + hi;                   // 16B group index 0..63
          float* ptr = &obuf[q * 256 + ((gp ^ (q & 15)) << 2)];
          f32x4 v4 = { o[ht][4*g2], o[ht][4*g2+1], o[ht][4*g2+2], o[ht][4*g2+3] };
          if (ph != 3) { f32x4 prev = *(f32x4*)ptr;
            #pragma unroll
            for (int z = 0; z < 4; z++) v4[z] += prev[z]; }
          if (ph != 0) { *(f32x4*)ptr = v4; }
          else {
            #pragma unroll
            for (int z = 0; z < 4; z++) v4[z] /= L;
            *(f32x4*)(outB + (size_t)qg * HEAD + ht * 32 + g2 * 8 + hi * 4) = v4;
          }
        }
    }
    __syncthreads();
  }
}

extern "C" void kernel_launch(void* const* d_in, const int* in_sizes, int n_in,
                              void* d_out, int out_size, void* d_ws, size_t ws_size,
                              hipStream_t stream) {
  const float* x  = (const float*)d_in[0];
  const float* Wq = (const float*)d_in[1];
  const float* Wk = (const float*)d_in[2];
  const float* Wv = (const float*)d_in[3];
  float* out = (float*)d_out;

  unsigned short* ws = (unsigned short*)d_ws;
  unsigned short* qb    = ws;                              // [16384][256] (Q pre-scaled)
  unsigned short* kb    = qb + (size_t)NTOK * HEAD;        // [16384][256] row-major
  unsigned short* vfrag = kb + (size_t)NTOK * HEAD;        // fragment-order V
  unsigned short* Wt    = vfrag + (size_t)NTOK * HEAD;     // [3][256][1024]
  unsigned short* xb    = Wt + (size_t)3 * HEAD * EMBED;   // [16384][1024]

  hipLaunchKernelGGL(wt_kernel, dim3(3 * 256 * EMBED / 256), dim3(256), 0, stream,
                     Wq, Wk, Wv, Wt);
  hipLaunchKernelGGL(xprep_kernel, dim3(NTOK * EMBED / (256 * 8)), dim3(256), 0, stream,
                     x, xb);
  hipLaunchKernelGGL(proj_kernel, dim3(768), dim3(256), 0, stream,
                     xb, Wt, qb, kb, vfrag);
  hipLaunchKernelGGL(attn_kernel, dim3(512), dim3(256), 0, stream,
                     qb, kb, vfrag, out);
}